// Round 13
// baseline (199.797 us; speedup 1.0000x reference)
//
#include <hip/hip_runtime.h>
#include <stdint.h>

typedef __attribute__((ext_vector_type(4))) float f32x4;
typedef __attribute__((ext_vector_type(8))) short short8v;
typedef __attribute__((ext_vector_type(4))) unsigned short ushort4v;
typedef __attribute__((ext_vector_type(8))) unsigned short ushort8v;

__device__ __forceinline__ unsigned short f2b(float x) {
  union { float f; unsigned int u; } c; c.f = x;
  unsigned int r = (c.u + 0x7fffu + ((c.u >> 16) & 1u)) >> 16;
  return (unsigned short)r;
}

__device__ __forceinline__ float b2f(unsigned short x) {
  union { unsigned int u; float f; } c; c.u = ((unsigned int)x) << 16;
  return c.f;
}

__device__ __forceinline__ void gload_lds16(const void* g, void* l) {
  __builtin_amdgcn_global_load_lds(
      (const __attribute__((address_space(1))) void*)g,
      (__attribute__((address_space(3))) void*)l, 16, 0, 0);
}

__device__ __forceinline__ f32x4 MFMA16(short8v a, short8v b, f32x4 c) {
  return __builtin_amdgcn_mfma_f32_16x16x32_bf16(a, b, c, 0, 0, 0);
}

template <int N>
__device__ __forceinline__ void wvm() {
  if constexpr (N == 8) asm volatile("s_waitcnt vmcnt(8)" ::: "memory");
  else if constexpr (N == 6) asm volatile("s_waitcnt vmcnt(6)" ::: "memory");
  else if constexpr (N == 4) asm volatile("s_waitcnt vmcnt(4)" ::: "memory");
  else if constexpr (N == 3) asm volatile("s_waitcnt vmcnt(3)" ::: "memory");
  else asm volatile("s_waitcnt vmcnt(0)" ::: "memory");
}

// XCD-aware bijective remap (kept where it measured neutral-to-positive:
// PV / oproj / QK^T-halves). Requires (gridDim.y*gridDim.z)%8==0.
__device__ __forceinline__ void xcd_swz(int& ex, int& ey, int& ez) {
  const int gx = gridDim.x, gy = gridDim.y, gz = gridDim.z;
  const int lid = blockIdx.x + gx * (blockIdx.y + gy * blockIdx.z);
  const int k = lid & 7;
  const int j = lid >> 3;
  const int lp = j / gx;
  ex = j - lp * gx;
  const int pe = (gy * gz) >> 3;
  const int panel = k * pe + lp;
  ey = panel % gy;
  ez = panel / gy;
}

// ---------------------------------------------------------------------------
// prep: z<4 -> transpose W_z (fp32 [k][n] -> bf16 [n][k]); z==4 -> cvt x->bf16.
__global__ __launch_bounds__(256) void prep(
    const float* __restrict__ x, const float* __restrict__ w0,
    const float* __restrict__ w1, const float* __restrict__ w2,
    const float* __restrict__ w3, unsigned short* __restrict__ xb,
    unsigned short* __restrict__ o0, unsigned short* __restrict__ o1,
    unsigned short* __restrict__ o2, unsigned short* __restrict__ o3) {
  const int z = blockIdx.z;
  if (z == 4) {
    const int linear = blockIdx.y * 16 + blockIdx.x;  // 0..255
    for (int i = linear * 256 + threadIdx.x; i < 1048576; i += 65536) {
      f32x4 a = *((const f32x4*)x + (size_t)i * 2);
      f32x4 b = *((const f32x4*)x + (size_t)i * 2 + 1);
      ushort8v o;
      o[0] = f2b(a[0]); o[1] = f2b(a[1]); o[2] = f2b(a[2]); o[3] = f2b(a[3]);
      o[4] = f2b(b[0]); o[5] = f2b(b[1]); o[6] = f2b(b[2]); o[7] = f2b(b[3]);
      *((ushort8v*)xb + i) = o;
    }
    return;
  }
  const float* W = z == 0 ? w0 : z == 1 ? w1 : z == 2 ? w2 : w3;
  unsigned short* WT = z == 0 ? o0 : z == 1 ? o1 : z == 2 ? o2 : o3;
  __shared__ float t[64][65];
  const int bi = blockIdx.y * 64, bj = blockIdx.x * 64;
#pragma unroll
  for (int i = 0; i < 16; ++i) {
    int idx = i * 256 + threadIdx.x;
    int r = idx >> 6, c = idx & 63;
    t[r][c] = W[(size_t)(bi + r) * 1024 + bj + c];
  }
  __syncthreads();
#pragma unroll
  for (int i = 0; i < 16; ++i) {
    int idx = i * 256 + threadIdx.x;
    int r = idx >> 6, c = idx & 63;
    WT[(size_t)(bj + r) * 1024 + bi + c] = f2b(t[c][r]);
  }
}

// In-place row softmax over 2048 bf16 scores.
__global__ __launch_bounds__(256) void softmax_bf16(unsigned short* __restrict__ S,
                                                    long long bstride) {
  unsigned short* row = S + (long long)blockIdx.y * bstride + (size_t)blockIdx.x * 2048;
  const int t = threadIdx.x;
  ushort8v u = *((const ushort8v*)row + t);
  float v[8];
#pragma unroll
  for (int j = 0; j < 8; ++j) v[j] = b2f(u[j]);
  float m = v[0];
#pragma unroll
  for (int j = 1; j < 8; ++j) m = fmaxf(m, v[j]);
#pragma unroll
  for (int o = 32; o; o >>= 1) m = fmaxf(m, __shfl_xor(m, o));
  __shared__ float red[4];
  const int wid = t >> 6, lane = t & 63;
  if (lane == 0) red[wid] = m;
  __syncthreads();
  m = fmaxf(fmaxf(red[0], red[1]), fmaxf(red[2], red[3]));
  float s = 0.f;
#pragma unroll
  for (int j = 0; j < 8; ++j) { v[j] = __expf(v[j] - m); s += v[j]; }
#pragma unroll
  for (int o = 32; o; o >>= 1) s += __shfl_xor(s, o);
  __syncthreads();
  if (lane == 0) red[wid] = s;
  __syncthreads();
  s = red[0] + red[1] + red[2] + red[3];
  const float inv = 1.f / s;
  ushort8v o8;
#pragma unroll
  for (int j = 0; j < 8; ++j) o8[j] = f2b(v[j] * inv);
  *((ushort8v*)row + t) = o8;
}

// Row softmax over 2048 fp32; writes bf16 P in place (fallback path only).
__global__ __launch_bounds__(256) void softmax_rows(float* __restrict__ S,
                                                    long long bstride) {
  float* row = S + (long long)blockIdx.y * bstride + (size_t)blockIdx.x * 2048;
  const int t = threadIdx.x;
  f32x4 a = *(const f32x4*)(row + t * 8);
  f32x4 b = *(const f32x4*)(row + t * 8 + 4);
  float m = fmaxf(fmaxf(fmaxf(a[0], a[1]), fmaxf(a[2], a[3])),
                  fmaxf(fmaxf(b[0], b[1]), fmaxf(b[2], b[3])));
#pragma unroll
  for (int o = 32; o; o >>= 1) m = fmaxf(m, __shfl_xor(m, o));
  __shared__ float red[4];
  const int wid = t >> 6, lane = t & 63;
  if (lane == 0) red[wid] = m;
  __syncthreads();
  m = fmaxf(fmaxf(red[0], red[1]), fmaxf(red[2], red[3]));
  float e[8];
  float s = 0.f;
#pragma unroll
  for (int j = 0; j < 4; ++j) { e[j] = __expf(a[j] - m); s += e[j]; }
#pragma unroll
  for (int j = 0; j < 4; ++j) { e[4 + j] = __expf(b[j] - m); s += e[4 + j]; }
#pragma unroll
  for (int o = 32; o; o >>= 1) s += __shfl_xor(s, o);
  __syncthreads();
  if (lane == 0) red[wid] = s;
  __syncthreads();
  s = red[0] + red[1] + red[2] + red[3];
  const float inv = 1.f / s;
  ushort8v o8;
#pragma unroll
  for (int j = 0; j < 8; ++j) o8[j] = f2b(e[j] * inv);
  __syncthreads();
  *((ushort8v*)row + t) = o8;
}

// ---------------------------------------------------------------------------
// Fused-QKV 128x128 GEMM — r8/r12 version (natural mapping, 64-68 us).
// BK=64, XOR-swizzled LDS, 32 KiB. grid (24,64).
// Epilogue: col seg 0 -> q, 1 -> k, 2 -> Vt[1024][8192].
__global__ __launch_bounds__(256, 2) void gemm_qkv128(
    const unsigned short* __restrict__ A,
    const unsigned short* __restrict__ B,
    unsigned short* __restrict__ Q, unsigned short* __restrict__ Kp,
    unsigned short* __restrict__ Vt,
    const float* __restrict__ bq, const float* __restrict__ bk,
    const float* __restrict__ bv) {
  __shared__ unsigned short As[128 * 64];
  __shared__ unsigned short Bs[128 * 64];
  const int tid = threadIdx.x;
  const int brow = blockIdx.y * 128, bcol = blockIdx.x * 128;
  const int wid = tid >> 6, lane = tid & 63;
  const int wr = (wid >> 1) * 64, wc = (wid & 1) * 64;
  const int lrow = lane & 15, kblk = lane >> 4;
  f32x4 acc[4][4] = {};
  for (int kk = 0; kk < 1024; kk += 64) {
#pragma unroll
    for (int g = 0; g < 4; ++g) {
      int idx = g * 256 + tid;
      int row = idx >> 3;
      int lk8 = ((idx & 7) ^ (row & 7)) << 3;
      gload_lds16(A + (size_t)(brow + row) * 1024 + kk + lk8, (char*)As + idx * 16);
      gload_lds16(B + (size_t)(bcol + row) * 1024 + kk + lk8, (char*)Bs + idx * 16);
    }
    __syncthreads();
#pragma unroll
    for (int ks = 0; ks < 2; ++ks) {
      short8v af[4], bf[4];
      const int kc = ks * 4 + kblk;
#pragma unroll
      for (int m = 0; m < 4; ++m) {
        const int row = wr + m * 16 + lrow;
        af[m] = *(const short8v*)(As + row * 64 + ((kc ^ (row & 7)) << 3));
      }
#pragma unroll
      for (int n = 0; n < 4; ++n) {
        const int row = wc + n * 16 + lrow;
        bf[n] = *(const short8v*)(Bs + row * 64 + ((kc ^ (row & 7)) << 3));
      }
#pragma unroll
      for (int m = 0; m < 4; ++m)
#pragma unroll
        for (int n = 0; n < 4; ++n)
          acc[m][n] = MFMA16(af[m], bf[n], acc[m][n]);
    }
    __syncthreads();
  }
  const int r0 = brow + wr + kblk * 4;
  const int c0 = bcol + wc + lrow;
  const int seg = bcol >> 10;
  if (seg < 2) {
    unsigned short* O = seg == 0 ? Q : Kp;
    const float* bb = seg == 0 ? bq : bk;
#pragma unroll
    for (int m = 0; m < 4; ++m)
#pragma unroll
      for (int n = 0; n < 4; ++n) {
        const int lc = c0 + n * 16 - seg * 1024;
        const float badd = bb[lc];
#pragma unroll
        for (int j = 0; j < 4; ++j)
          O[(size_t)(r0 + m * 16 + j) * 1024 + lc] = f2b(acc[m][n][j] + badd);
      }
  } else {
#pragma unroll
    for (int m = 0; m < 4; ++m)
#pragma unroll
      for (int n = 0; n < 4; ++n) {
        const int lc = c0 + n * 16 - 2048;
        const float badd = bv[lc];
        ushort4v pk;
#pragma unroll
        for (int j = 0; j < 4; ++j) pk[j] = f2b(acc[m][n][j] + badd);
        *(ushort4v*)(Vt + (size_t)lc * 8192 + r0 + m * 16) = pk;
      }
  }
}

// ---------------------------------------------------------------------------
// BMx256 8-phase GEMM (r10/r12 config; QK^T-halves, PV, out-proj).
// EPI: 0 = fp32 out (scale + opt bias), 1 = bf16 out (scale + opt bias)
template <int EPI, int BM>
__global__ __launch_bounds__(512, 2) void gemm256(
    const unsigned short* __restrict__ A, int lda,
    const unsigned short* __restrict__ B, int ldb,
    void* __restrict__ C0, int ldc, const float* __restrict__ bias0,
    float scale, int K, long long bsA, long long bsB, long long bsC) {
  extern __shared__ __align__(16) char smem[];
  constexpr int ABY = BM * 64;
  constexpr int KHS = ABY + 16384;
  constexpr int SBUF = 2 * KHS;
  constexpr int MF = BM / 32;
  constexpr int FH = MF / 2;
  constexpr int AL = BM / 128;
  constexpr int L = AL + 2;

  const int tid = threadIdx.x;
  int ex, ey, ez;
  xcd_swz(ex, ey, ez);
  A += (long long)ez * bsA;
  B += (long long)ez * bsB;
  const int blkrow = ey * BM, blkcol = ex * 256;
  const int lane = tid & 63, wid = tid >> 6;
  const int kblk = lane >> 4, l15 = lane & 15;
  const int arw = (wid >> 2) * (BM / 2) + l15;
  const int brw = (wid & 3) * 64 + l15;
  const int aoff = arw * 64 + ((kblk ^ ((arw >> 1) & 3)) << 4);
  const int boff = ABY + brw * 64 + ((kblk ^ ((brw >> 1) & 3)) << 4);
  const int srow = tid >> 2;
  const int scc = (((tid & 3) ^ ((srow >> 1) & 3)) << 3);
  const unsigned short* ag = A + (size_t)(blkrow + srow) * lda + scc;
  const unsigned short* bg = B + (size_t)(blkcol + srow) * ldb + scc;

  auto stA = [&](char* buf, int kt, int kh) {
    const unsigned short* g = ag + kt * 64 + kh * 32;
    char* l = buf + kh * KHS + tid * 16;
#pragma unroll
    for (int rr = 0; rr < AL; ++rr)
      gload_lds16(g + (size_t)(rr * 128) * lda, l + rr * 8192);
  };
  auto stB = [&](char* buf, int kt, int kh) {
    const unsigned short* g = bg + kt * 64 + kh * 32;
    char* l = buf + ABY + kh * KHS + tid * 16;
    gload_lds16(g, l);
    gload_lds16(g + (size_t)128 * ldb, l + 8192);
  };

  f32x4 acc[MF][4] = {};
  short8v af[4], bf[4];

#define LDAH(BUF, KK, MB)                                                     \
  { _Pragma("unroll") for (int m_ = 0; m_ < FH; ++m_)                         \
      af[m_] = *(const short8v*)((BUF) + (KK)*KHS + aoff + ((MB) + m_) * 1024); }
#define LDB4(BUF, KK)                                                         \
  { _Pragma("unroll") for (int n_ = 0; n_ < 4; ++n_)                          \
      bf[n_] = *(const short8v*)((BUF) + (KK)*KHS + boff + n_ * 1024); }
#define MMH(MH)                                                               \
  { _Pragma("unroll") for (int m_ = 0; m_ < FH; ++m_)                         \
      _Pragma("unroll") for (int n_ = 0; n_ < 4; ++n_)                        \
        acc[(MH)*FH + m_][n_] = MFMA16(af[m_], bf[n_], acc[(MH)*FH + m_][n_]); }
#define BAR __builtin_amdgcn_s_barrier()
#define WLGKM0 asm volatile("s_waitcnt lgkmcnt(0)" ::: "memory")

  const int NT = K >> 6;
  stA(smem, 0, 0); stB(smem, 0, 0); stA(smem, 0, 1); stB(smem, 0, 1);
  wvm<L>();
  BAR;
  for (int t = 0; t < NT; ++t) {
    char* cur = smem + (t & 1) * SBUF;
    char* nxt = smem + ((t + 1) & 1) * SBUF;
    const bool pf = (t + 1 < NT);
    LDAH(cur, 0, 0);
    LDB4(cur, 0);
    if (pf) { stA(nxt, t + 1, 0); stB(nxt, t + 1, 0); }
    BAR; WLGKM0;
    __builtin_amdgcn_s_setprio(1);
    MMH(0);
    __builtin_amdgcn_s_setprio(0);
    BAR;
    LDAH(cur, 0, FH);
    if (pf) { stA(nxt, t + 1, 1); stB(nxt, t + 1, 1); }
    BAR; WLGKM0;
    __builtin_amdgcn_s_setprio(1);
    MMH(1);
    __builtin_amdgcn_s_setprio(0);
    if (pf) wvm<2 * L>(); else wvm<0>();
    BAR;
    LDAH(cur, 1, 0);
    LDB4(cur, 1);
    BAR; WLGKM0;
    __builtin_amdgcn_s_setprio(1);
    MMH(0);
    __builtin_amdgcn_s_setprio(0);
    BAR;
    LDAH(cur, 1, FH);
    BAR; WLGKM0;
    __builtin_amdgcn_s_setprio(1);
    MMH(1);
    __builtin_amdgcn_s_setprio(0);
    if (pf) wvm<L>();
    BAR;
  }

  const int gr0 = blkrow + (wid >> 2) * (BM / 2) + kblk * 4;
  const int gc0 = blkcol + (wid & 3) * 64 + l15;
  if (EPI == 0) {
    float* C = (float*)C0 + (long long)ez * bsC;
#pragma unroll
    for (int mi = 0; mi < MF; ++mi)
#pragma unroll
      for (int n = 0; n < 4; ++n) {
        const int gc = gc0 + n * 16;
        const float badd = bias0 ? bias0[gc] : 0.f;
#pragma unroll
        for (int j = 0; j < 4; ++j)
          C[(size_t)(gr0 + mi * 16 + j) * ldc + gc] = acc[mi][n][j] * scale + badd;
      }
  } else {
    unsigned short* C = (unsigned short*)C0 + (long long)ez * bsC;
#pragma unroll
    for (int mi = 0; mi < MF; ++mi)
#pragma unroll
      for (int n = 0; n < 4; ++n) {
        const int gc = gc0 + n * 16;
        const float badd = bias0 ? bias0[gc] : 0.f;
#pragma unroll
        for (int j = 0; j < 4; ++j)
          C[(size_t)(gr0 + mi * 16 + j) * ldc + gc] = f2b(acc[mi][n][j] * scale + badd);
      }
  }
#undef LDAH
#undef LDB4
#undef MMH
#undef BAR
#undef WLGKM0
}

// ---------------------------------------------------------------------------
// fallback m97-style 128x128 GEMM (small-ws plan only)
template <int OMODE, bool BIAS, bool SCALE>
__global__ __launch_bounds__(256, 2) void gemm_bt(
    const unsigned short* __restrict__ A, int lda,
    const unsigned short* __restrict__ B, int ldb,
    void* __restrict__ Cp, int ldc,
    const float* __restrict__ bias, float scale, int K,
    long long bsA, long long bsB, long long bsC) {
  __shared__ unsigned short As[128 * 32];
  __shared__ unsigned short Bs[128 * 32];
  const int tid = threadIdx.x;
  A += (long long)blockIdx.z * bsA;
  B += (long long)blockIdx.z * bsB;
  const int brow = blockIdx.y * 128, bcol = blockIdx.x * 128;
  const int wid = tid >> 6, lane = tid & 63;
  const int wr = (wid >> 1) * 64, wc = (wid & 1) * 64;
  const int lrow = lane & 15, kblk = lane >> 4;
  f32x4 acc[4][4] = {};
  for (int kk = 0; kk < K; kk += 32) {
#pragma unroll
    for (int r = 0; r < 2; ++r) {
      int idx = r * 256 + tid;
      int row = idx >> 2, seg = (idx & 3) * 8;
      gload_lds16(A + (size_t)(brow + row) * lda + kk + seg, (char*)As + idx * 16);
      gload_lds16(B + (size_t)(bcol + row) * ldb + kk + seg, (char*)Bs + idx * 16);
    }
    __syncthreads();
    short8v af[4], bv[4];
#pragma unroll
    for (int m = 0; m < 4; ++m)
      af[m] = *(const short8v*)(As + (wr + m * 16 + lrow) * 32 + kblk * 8);
#pragma unroll
    for (int n = 0; n < 4; ++n)
      bv[n] = *(const short8v*)(Bs + (wc + n * 16 + lrow) * 32 + kblk * 8);
#pragma unroll
    for (int m = 0; m < 4; ++m)
#pragma unroll
      for (int n = 0; n < 4; ++n)
        acc[m][n] = MFMA16(af[m], bv[n], acc[m][n]);
    __syncthreads();
  }
  const int r0 = brow + wr + kblk * 4;
  const int c0 = bcol + wc + lrow;
  if (OMODE == 0) {
    float* C = (float*)Cp + (long long)blockIdx.z * bsC;
#pragma unroll
    for (int m = 0; m < 4; ++m)
#pragma unroll
      for (int n = 0; n < 4; ++n) {
        const int cc = c0 + n * 16;
        const float badd = BIAS ? bias[cc] : 0.f;
#pragma unroll
        for (int j = 0; j < 4; ++j) {
          float v = acc[m][n][j];
          if (SCALE) v *= scale;
          C[(size_t)(r0 + m * 16 + j) * ldc + cc] = v + badd;
        }
      }
  } else if (OMODE == 1) {
    unsigned short* C = (unsigned short*)Cp + (long long)blockIdx.z * bsC;
#pragma unroll
    for (int m = 0; m < 4; ++m)
#pragma unroll
      for (int n = 0; n < 4; ++n) {
        const int cc = c0 + n * 16;
        const float badd = BIAS ? bias[cc] : 0.f;
#pragma unroll
        for (int j = 0; j < 4; ++j) {
          float v = acc[m][n][j];
          if (SCALE) v *= scale;
          C[(size_t)(r0 + m * 16 + j) * ldc + cc] = f2b(v + badd);
        }
      }
  } else {
    unsigned short* C = (unsigned short*)Cp + (long long)blockIdx.z * bsC;
#pragma unroll
    for (int m = 0; m < 4; ++m)
#pragma unroll
      for (int n = 0; n < 4; ++n) {
        const int cc = c0 + n * 16;
        const float badd = BIAS ? bias[cc] : 0.f;
        ushort4v pk;
#pragma unroll
        for (int j = 0; j < 4; ++j) {
          float v = acc[m][n][j];
          if (SCALE) v *= scale;
          pk[j] = f2b(v + badd);
        }
        *(ushort4v*)(C + (size_t)cc * ldc + (r0 + m * 16)) = pk;
      }
  }
}

__global__ __launch_bounds__(256) void cvt_batch(const float* __restrict__ in,
                                                 unsigned short* __restrict__ out,
                                                 int n8) {
  for (int i = blockIdx.x * 256 + threadIdx.x; i < n8; i += gridDim.x * 256) {
    f32x4 a = *((const f32x4*)in + (size_t)i * 2);
    f32x4 b = *((const f32x4*)in + (size_t)i * 2 + 1);
    ushort8v o;
    o[0] = f2b(a[0]); o[1] = f2b(a[1]); o[2] = f2b(a[2]); o[3] = f2b(a[3]);
    o[4] = f2b(b[0]); o[5] = f2b(b[1]); o[6] = f2b(b[2]); o[7] = f2b(b[3]);
    *((ushort8v*)out + i) = o;
  }
}

extern "C" void kernel_launch(void* const* d_in, const int* in_sizes, int n_in,
                              void* d_out, int out_size, void* d_ws, size_t ws_size,
                              hipStream_t stream) {
  const float* x  = (const float*)d_in[0];
  const float* wq = (const float*)d_in[1];
  const float* bq = (const float*)d_in[2];
  const float* wk = (const float*)d_in[3];
  const float* bk = (const float*)d_in[4];
  const float* wv = (const float*)d_in[5];
  const float* bv = (const float*)d_in[6];
  const float* wo = (const float*)d_in[7];
  const float* bo = (const float*)d_in[8];
  float* out = (float*)d_out;
  char* ws = (char*)d_ws;

  const long long WELEM = 1024LL * 1024;
  const long long BATCH = 2048LL * 1024;
  const long long FULL  = 4 * BATCH;
  const long long SELEM = 2048LL * 2048;   // per-batch scores (elems)

  const size_t need_A = 8388608ull + 5ull * 16777216 + 4ull * 16777216;
  const size_t need_C = 8388608ull + 4ull * 4194304 + 16777216ull;

  if (ws_size >= need_A) {
    unsigned short* wqT = (unsigned short*)ws;
    unsigned short* wkT = wqT + WELEM;
    unsigned short* wvT = wkT + WELEM;   // wqT..wvT contiguous => [3072][1024]
    unsigned short* woT = wvT + WELEM;
    unsigned short* xb  = woT + WELEM;
    unsigned short* qb  = xb + FULL;
    unsigned short* kb  = qb + FULL;
    unsigned short* vt  = kb + FULL;     // Vt[1024][8192]
    unsigned short* ao  = vt + FULL;
    unsigned short* S   = ao + FULL;     // bf16 scores [4][2048][2048]

    hipFuncSetAttribute(reinterpret_cast<const void*>(&gemm256<1, 128>),
                        hipFuncAttributeMaxDynamicSharedMemorySize, 98304);
    hipFuncSetAttribute(reinterpret_cast<const void*>(&gemm256<0, 128>),
                        hipFuncAttributeMaxDynamicSharedMemorySize, 98304);

    // prep: weight transposes (z=0..3) + x->bf16 (z=4) in ONE launch
    prep<<<dim3(16, 16, 5), 256, 0, stream>>>(x, wq, wk, wv, wo, xb,
                                              wqT, wkT, wvT, woT);

    // fused QKV (natural mapping, r8/r12 config): grid (24,64)
    gemm_qkv128<<<dim3(24, 64), 256, 0, stream>>>(
        xb, wqT, qb, kb, vt, bq, bk, bv);
    // QK^T as two PV-shaped halves (N=1024 each), grid (4,16,4) = 256 blocks:
    //   half 0: B = kb rows [0,1024)    -> S cols [0,1024)
    //   half 1: B = kb rows [1024,2048) -> S cols [1024,2048)
    gemm256<1, 128><<<dim3(4, 16, 4), 512, 98304, stream>>>(
        qb, 1024, kb, 1024, S, 2048, nullptr, 0.03125f, 1024,
        BATCH, BATCH, SELEM);
    gemm256<1, 128><<<dim3(4, 16, 4), 512, 98304, stream>>>(
        qb, 1024, kb + 1024LL * 1024, 1024, S + 1024, 2048, nullptr,
        0.03125f, 1024, BATCH, BATCH, SELEM);
    softmax_bf16<<<dim3(2048, 4), 256, 0, stream>>>(S, SELEM);
    // PV (batched): grid (4,16,4)
    gemm256<1, 128><<<dim3(4, 16, 4), 512, 98304, stream>>>(
        S, 2048, vt, 8192, ao, 1024, nullptr, 1.f, 2048,
        SELEM, 2048, BATCH);
    // out-proj: grid (4,64)
    gemm256<0, 128><<<dim3(4, 64, 1), 512, 98304, stream>>>(
        ao, 1024, woT, 1024, out, 1024, bo, 1.f, 1024, 0, 0, 0);
  } else if (ws_size >= need_C) {
    unsigned short* wqT = (unsigned short*)ws;
    unsigned short* wkT = wqT + WELEM;
    unsigned short* wvT = wkT + WELEM;
    unsigned short* woT = wvT + WELEM;
    unsigned short* xb  = woT + WELEM;
    unsigned short* qb  = xb + BATCH;
    unsigned short* kb  = qb + BATCH;
    unsigned short* vtb = kb + BATCH;
    float* S = (float*)(vtb + BATCH);

    prep<<<dim3(16, 16, 4), 256, 0, stream>>>(x, wq, wk, wv, wo, xb,
                                              wqT, wkT, wvT, woT);

    for (int b = 0; b < 4; ++b) {
      cvt_batch<<<1024, 256, 0, stream>>>(x + b * BATCH, xb, (int)(BATCH / 8));
      dim3 gqkv(8, 16);
      gemm_bt<1, true, false><<<gqkv, 256, 0, stream>>>(xb, 1024, wqT, 1024, qb, 1024, bq, 1.f, 1024, 0, 0, 0);
      gemm_bt<1, true, false><<<gqkv, 256, 0, stream>>>(xb, 1024, wkT, 1024, kb, 1024, bk, 1.f, 1024, 0, 0, 0);
      gemm_bt<2, true, false><<<gqkv, 256, 0, stream>>>(xb, 1024, wvT, 1024, vtb, 2048, bv, 1.f, 1024, 0, 0, 0);
      gemm_bt<0, false, true><<<dim3(16, 16), 256, 0, stream>>>(
          qb, 1024, kb, 1024, S, 2048, nullptr, 0.03125f, 1024, 0, 0, 0);
      softmax_rows<<<dim3(2048, 1), 256, 0, stream>>>(S, 0);
      gemm_bt<1, false, false><<<dim3(8, 16), 256, 0, stream>>>(
          (const unsigned short*)S, 4096, vtb, 2048, xb, 1024, nullptr, 1.f, 2048, 0, 0, 0);
      gemm_bt<0, true, false><<<dim3(8, 16), 256, 0, stream>>>(
          xb, 1024, woT, 1024, out + b * BATCH, 1024, bo, 1.f, 1024, 0, 0, 0);
    }
  }
}

// Round 14
// 187.636 us; speedup vs baseline: 1.0648x; 1.0648x over previous
//
#include <hip/hip_runtime.h>
#include <stdint.h>

typedef __attribute__((ext_vector_type(4))) float f32x4;
typedef __attribute__((ext_vector_type(8))) short short8v;
typedef __attribute__((ext_vector_type(4))) unsigned short ushort4v;
typedef __attribute__((ext_vector_type(8))) unsigned short ushort8v;

__device__ __forceinline__ unsigned short f2b(float x) {
  union { float f; unsigned int u; } c; c.f = x;
  unsigned int r = (c.u + 0x7fffu + ((c.u >> 16) & 1u)) >> 16;
  return (unsigned short)r;
}

__device__ __forceinline__ float b2f(unsigned short x) {
  union { unsigned int u; float f; } c; c.u = ((unsigned int)x) << 16;
  return c.f;
}

__device__ __forceinline__ void gload_lds16(const void* g, void* l) {
  __builtin_amdgcn_global_load_lds(
      (const __attribute__((address_space(1))) void*)g,
      (__attribute__((address_space(3))) void*)l, 16, 0, 0);
}

__device__ __forceinline__ f32x4 MFMA16(short8v a, short8v b, f32x4 c) {
  return __builtin_amdgcn_mfma_f32_16x16x32_bf16(a, b, c, 0, 0, 0);
}

template <int N>
__device__ __forceinline__ void wvm() {
  if constexpr (N == 8) asm volatile("s_waitcnt vmcnt(8)" ::: "memory");
  else if constexpr (N == 6) asm volatile("s_waitcnt vmcnt(6)" ::: "memory");
  else if constexpr (N == 4) asm volatile("s_waitcnt vmcnt(4)" ::: "memory");
  else if constexpr (N == 3) asm volatile("s_waitcnt vmcnt(3)" ::: "memory");
  else asm volatile("s_waitcnt vmcnt(0)" ::: "memory");
}

// XCD-aware bijective remap — used where it measured a win (PV/oproj).
__device__ __forceinline__ void xcd_swz(int& ex, int& ey, int& ez) {
  const int gx = gridDim.x, gy = gridDim.y, gz = gridDim.z;
  const int lid = blockIdx.x + gx * (blockIdx.y + gy * blockIdx.z);
  const int k = lid & 7;
  const int j = lid >> 3;
  const int lp = j / gx;
  ex = j - lp * gx;
  const int pe = (gy * gz) >> 3;
  const int panel = k * pe + lp;
  ey = panel % gy;
  ez = panel / gy;
}

// ---------------------------------------------------------------------------
// prep: z<4 -> transpose W_z (fp32 [k][n] -> bf16 [n][k]); z==4 -> cvt x->bf16.
__global__ __launch_bounds__(256) void prep(
    const float* __restrict__ x, const float* __restrict__ w0,
    const float* __restrict__ w1, const float* __restrict__ w2,
    const float* __restrict__ w3, unsigned short* __restrict__ xb,
    unsigned short* __restrict__ o0, unsigned short* __restrict__ o1,
    unsigned short* __restrict__ o2, unsigned short* __restrict__ o3) {
  const int z = blockIdx.z;
  if (z == 4) {
    const int linear = blockIdx.y * 16 + blockIdx.x;  // 0..255
    for (int i = linear * 256 + threadIdx.x; i < 1048576; i += 65536) {
      f32x4 a = *((const f32x4*)x + (size_t)i * 2);
      f32x4 b = *((const f32x4*)x + (size_t)i * 2 + 1);
      ushort8v o;
      o[0] = f2b(a[0]); o[1] = f2b(a[1]); o[2] = f2b(a[2]); o[3] = f2b(a[3]);
      o[4] = f2b(b[0]); o[5] = f2b(b[1]); o[6] = f2b(b[2]); o[7] = f2b(b[3]);
      *((ushort8v*)xb + i) = o;
    }
    return;
  }
  const float* W = z == 0 ? w0 : z == 1 ? w1 : z == 2 ? w2 : w3;
  unsigned short* WT = z == 0 ? o0 : z == 1 ? o1 : z == 2 ? o2 : o3;
  __shared__ float t[64][65];
  const int bi = blockIdx.y * 64, bj = blockIdx.x * 64;
#pragma unroll
  for (int i = 0; i < 16; ++i) {
    int idx = i * 256 + threadIdx.x;
    int r = idx >> 6, c = idx & 63;
    t[r][c] = W[(size_t)(bi + r) * 1024 + bj + c];
  }
  __syncthreads();
#pragma unroll
  for (int i = 0; i < 16; ++i) {
    int idx = i * 256 + threadIdx.x;
    int r = idx >> 6, c = idx & 63;
    WT[(size_t)(bj + r) * 1024 + bi + c] = f2b(t[c][r]);
  }
}

// In-place row softmax over 2048 bf16 scores.
__global__ __launch_bounds__(256) void softmax_bf16(unsigned short* __restrict__ S,
                                                    long long bstride) {
  unsigned short* row = S + (long long)blockIdx.y * bstride + (size_t)blockIdx.x * 2048;
  const int t = threadIdx.x;
  ushort8v u = *((const ushort8v*)row + t);
  float v[8];
#pragma unroll
  for (int j = 0; j < 8; ++j) v[j] = b2f(u[j]);
  float m = v[0];
#pragma unroll
  for (int j = 1; j < 8; ++j) m = fmaxf(m, v[j]);
#pragma unroll
  for (int o = 32; o; o >>= 1) m = fmaxf(m, __shfl_xor(m, o));
  __shared__ float red[4];
  const int wid = t >> 6, lane = t & 63;
  if (lane == 0) red[wid] = m;
  __syncthreads();
  m = fmaxf(fmaxf(red[0], red[1]), fmaxf(red[2], red[3]));
  float s = 0.f;
#pragma unroll
  for (int j = 0; j < 8; ++j) { v[j] = __expf(v[j] - m); s += v[j]; }
#pragma unroll
  for (int o = 32; o; o >>= 1) s += __shfl_xor(s, o);
  __syncthreads();
  if (lane == 0) red[wid] = s;
  __syncthreads();
  s = red[0] + red[1] + red[2] + red[3];
  const float inv = 1.f / s;
  ushort8v o8;
#pragma unroll
  for (int j = 0; j < 8; ++j) o8[j] = f2b(v[j] * inv);
  *((ushort8v*)row + t) = o8;
}

// Row softmax over 2048 fp32; writes bf16 P in place (fallback path only).
__global__ __launch_bounds__(256) void softmax_rows(float* __restrict__ S,
                                                    long long bstride) {
  float* row = S + (long long)blockIdx.y * bstride + (size_t)blockIdx.x * 2048;
  const int t = threadIdx.x;
  f32x4 a = *(const f32x4*)(row + t * 8);
  f32x4 b = *(const f32x4*)(row + t * 8 + 4);
  float m = fmaxf(fmaxf(fmaxf(a[0], a[1]), fmaxf(a[2], a[3])),
                  fmaxf(fmaxf(b[0], b[1]), fmaxf(b[2], b[3])));
#pragma unroll
  for (int o = 32; o; o >>= 1) m = fmaxf(m, __shfl_xor(m, o));
  __shared__ float red[4];
  const int wid = t >> 6, lane = t & 63;
  if (lane == 0) red[wid] = m;
  __syncthreads();
  m = fmaxf(fmaxf(red[0], red[1]), fmaxf(red[2], red[3]));
  float e[8];
  float s = 0.f;
#pragma unroll
  for (int j = 0; j < 4; ++j) { e[j] = __expf(a[j] - m); s += e[j]; }
#pragma unroll
  for (int j = 0; j < 4; ++j) { e[4 + j] = __expf(b[j] - m); s += e[4 + j]; }
#pragma unroll
  for (int o = 32; o; o >>= 1) s += __shfl_xor(s, o);
  __syncthreads();
  if (lane == 0) red[wid] = s;
  __syncthreads();
  s = red[0] + red[1] + red[2] + red[3];
  const float inv = 1.f / s;
  ushort8v o8;
#pragma unroll
  for (int j = 0; j < 8; ++j) o8[j] = f2b(e[j] * inv);
  __syncthreads();
  *((ushort8v*)row + t) = o8;
}

// ---------------------------------------------------------------------------
// Fused-QKV 128x128 GEMM — natural block mapping (measured best: 64-68 us,
// 736 TF). BK=64, XOR-swizzled LDS, 32 KiB. grid (24,64).
// Epilogue: col seg 0 -> q, 1 -> k, 2 -> Vt[1024][8192].
__global__ __launch_bounds__(256, 2) void gemm_qkv128(
    const unsigned short* __restrict__ A,
    const unsigned short* __restrict__ B,
    unsigned short* __restrict__ Q, unsigned short* __restrict__ Kp,
    unsigned short* __restrict__ Vt,
    const float* __restrict__ bq, const float* __restrict__ bk,
    const float* __restrict__ bv) {
  __shared__ unsigned short As[128 * 64];
  __shared__ unsigned short Bs[128 * 64];
  const int tid = threadIdx.x;
  const int brow = blockIdx.y * 128, bcol = blockIdx.x * 128;
  const int wid = tid >> 6, lane = tid & 63;
  const int wr = (wid >> 1) * 64, wc = (wid & 1) * 64;
  const int lrow = lane & 15, kblk = lane >> 4;
  f32x4 acc[4][4] = {};
  for (int kk = 0; kk < 1024; kk += 64) {
#pragma unroll
    for (int g = 0; g < 4; ++g) {
      int idx = g * 256 + tid;
      int row = idx >> 3;
      int lk8 = ((idx & 7) ^ (row & 7)) << 3;
      gload_lds16(A + (size_t)(brow + row) * 1024 + kk + lk8, (char*)As + idx * 16);
      gload_lds16(B + (size_t)(bcol + row) * 1024 + kk + lk8, (char*)Bs + idx * 16);
    }
    __syncthreads();
#pragma unroll
    for (int ks = 0; ks < 2; ++ks) {
      short8v af[4], bf[4];
      const int kc = ks * 4 + kblk;
#pragma unroll
      for (int m = 0; m < 4; ++m) {
        const int row = wr + m * 16 + lrow;
        af[m] = *(const short8v*)(As + row * 64 + ((kc ^ (row & 7)) << 3));
      }
#pragma unroll
      for (int n = 0; n < 4; ++n) {
        const int row = wc + n * 16 + lrow;
        bf[n] = *(const short8v*)(Bs + row * 64 + ((kc ^ (row & 7)) << 3));
      }
#pragma unroll
      for (int m = 0; m < 4; ++m)
#pragma unroll
        for (int n = 0; n < 4; ++n)
          acc[m][n] = MFMA16(af[m], bf[n], acc[m][n]);
    }
    __syncthreads();
  }
  const int r0 = brow + wr + kblk * 4;
  const int c0 = bcol + wc + lrow;
  const int seg = bcol >> 10;
  if (seg < 2) {
    unsigned short* O = seg == 0 ? Q : Kp;
    const float* bb = seg == 0 ? bq : bk;
#pragma unroll
    for (int m = 0; m < 4; ++m)
#pragma unroll
      for (int n = 0; n < 4; ++n) {
        const int lc = c0 + n * 16 - seg * 1024;
        const float badd = bb[lc];
#pragma unroll
        for (int j = 0; j < 4; ++j)
          O[(size_t)(r0 + m * 16 + j) * 1024 + lc] = f2b(acc[m][n][j] + badd);
      }
  } else {
#pragma unroll
    for (int m = 0; m < 4; ++m)
#pragma unroll
      for (int n = 0; n < 4; ++n) {
        const int lc = c0 + n * 16 - 2048;
        const float badd = bv[lc];
        ushort4v pk;
#pragma unroll
        for (int j = 0; j < 4; ++j) pk[j] = f2b(acc[m][n][j] + badd);
        *(ushort4v*)(Vt + (size_t)lc * 8192 + r0 + m * 16) = pk;
      }
  }
}

// ---------------------------------------------------------------------------
// Generalized batched 128x128 high-occupancy GEMM (QK^T; measured ~49 us).
// EPI: 0 = fp32 out (+opt bias), 1 = bf16 out (scale, +opt bias)
template <int EPI>
__global__ __launch_bounds__(256, 2) void gemm128(
    const unsigned short* __restrict__ A, int lda,
    const unsigned short* __restrict__ B, int ldb,
    void* __restrict__ Cp, int ldc, const float* __restrict__ bias,
    float scale, int K, long long bsA, long long bsB, long long bsC) {
  __shared__ unsigned short As[128 * 64];
  __shared__ unsigned short Bs[128 * 64];
  const int tid = threadIdx.x;
  const int z = blockIdx.z;
  A += (long long)z * bsA;
  B += (long long)z * bsB;
  const int brow = blockIdx.y * 128, bcol = blockIdx.x * 128;
  const int wid = tid >> 6, lane = tid & 63;
  const int wr = (wid >> 1) * 64, wc = (wid & 1) * 64;
  const int lrow = lane & 15, kblk = lane >> 4;
  f32x4 acc[4][4] = {};
  for (int kk = 0; kk < K; kk += 64) {
#pragma unroll
    for (int g = 0; g < 4; ++g) {
      int idx = g * 256 + tid;
      int row = idx >> 3;
      int lk8 = ((idx & 7) ^ (row & 7)) << 3;
      gload_lds16(A + (size_t)(brow + row) * lda + kk + lk8, (char*)As + idx * 16);
      gload_lds16(B + (size_t)(bcol + row) * ldb + kk + lk8, (char*)Bs + idx * 16);
    }
    __syncthreads();
#pragma unroll
    for (int ks = 0; ks < 2; ++ks) {
      short8v af[4], bf[4];
      const int kc = ks * 4 + kblk;
#pragma unroll
      for (int m = 0; m < 4; ++m) {
        const int row = wr + m * 16 + lrow;
        af[m] = *(const short8v*)(As + row * 64 + ((kc ^ (row & 7)) << 3));
      }
#pragma unroll
      for (int n = 0; n < 4; ++n) {
        const int row = wc + n * 16 + lrow;
        bf[n] = *(const short8v*)(Bs + row * 64 + ((kc ^ (row & 7)) << 3));
      }
#pragma unroll
      for (int m = 0; m < 4; ++m)
#pragma unroll
        for (int n = 0; n < 4; ++n)
          acc[m][n] = MFMA16(af[m], bf[n], acc[m][n]);
    }
    __syncthreads();
  }
  const int r0 = brow + wr + kblk * 4;
  const int c0 = bcol + wc + lrow;
  if (EPI == 0) {
    float* C = (float*)Cp + (long long)z * bsC;
#pragma unroll
    for (int m = 0; m < 4; ++m)
#pragma unroll
      for (int n = 0; n < 4; ++n) {
        const int gc = c0 + n * 16;
        const float badd = bias ? bias[gc] : 0.f;
#pragma unroll
        for (int j = 0; j < 4; ++j)
          C[(size_t)(r0 + m * 16 + j) * ldc + gc] = acc[m][n][j] * scale + badd;
      }
  } else {
    unsigned short* C = (unsigned short*)Cp + (long long)z * bsC;
#pragma unroll
    for (int m = 0; m < 4; ++m)
#pragma unroll
      for (int n = 0; n < 4; ++n) {
        const int gc = c0 + n * 16;
        const float badd = bias ? bias[gc] : 0.f;
#pragma unroll
        for (int j = 0; j < 4; ++j)
          C[(size_t)(r0 + m * 16 + j) * ldc + gc] = f2b(acc[m][n][j] * scale + badd);
      }
  }
}

// ---------------------------------------------------------------------------
// BMx256 8-phase GEMM (kept ONLY for PV and out-proj; measured 980-1000 TF).
// EPI: 0 = fp32 out (scale + opt bias), 1 = bf16 out (scale + opt bias)
template <int EPI, int BM>
__global__ __launch_bounds__(512, 2) void gemm256(
    const unsigned short* __restrict__ A, int lda,
    const unsigned short* __restrict__ B, int ldb,
    void* __restrict__ C0, int ldc, const float* __restrict__ bias0,
    float scale, int K, long long bsA, long long bsB, long long bsC) {
  extern __shared__ __align__(16) char smem[];
  constexpr int ABY = BM * 64;
  constexpr int KHS = ABY + 16384;
  constexpr int SBUF = 2 * KHS;
  constexpr int MF = BM / 32;
  constexpr int FH = MF / 2;
  constexpr int AL = BM / 128;
  constexpr int L = AL + 2;

  const int tid = threadIdx.x;
  int ex, ey, ez;
  xcd_swz(ex, ey, ez);
  A += (long long)ez * bsA;
  B += (long long)ez * bsB;
  const int blkrow = ey * BM, blkcol = ex * 256;
  const int lane = tid & 63, wid = tid >> 6;
  const int kblk = lane >> 4, l15 = lane & 15;
  const int arw = (wid >> 2) * (BM / 2) + l15;
  const int brw = (wid & 3) * 64 + l15;
  const int aoff = arw * 64 + ((kblk ^ ((arw >> 1) & 3)) << 4);
  const int boff = ABY + brw * 64 + ((kblk ^ ((brw >> 1) & 3)) << 4);
  const int srow = tid >> 2;
  const int scc = (((tid & 3) ^ ((srow >> 1) & 3)) << 3);
  const unsigned short* ag = A + (size_t)(blkrow + srow) * lda + scc;
  const unsigned short* bg = B + (size_t)(blkcol + srow) * ldb + scc;

  auto stA = [&](char* buf, int kt, int kh) {
    const unsigned short* g = ag + kt * 64 + kh * 32;
    char* l = buf + kh * KHS + tid * 16;
#pragma unroll
    for (int rr = 0; rr < AL; ++rr)
      gload_lds16(g + (size_t)(rr * 128) * lda, l + rr * 8192);
  };
  auto stB = [&](char* buf, int kt, int kh) {
    const unsigned short* g = bg + kt * 64 + kh * 32;
    char* l = buf + ABY + kh * KHS + tid * 16;
    gload_lds16(g, l);
    gload_lds16(g + (size_t)128 * ldb, l + 8192);
  };

  f32x4 acc[MF][4] = {};
  short8v af[4], bf[4];

#define LDAH(BUF, KK, MB)                                                     \
  { _Pragma("unroll") for (int m_ = 0; m_ < FH; ++m_)                         \
      af[m_] = *(const short8v*)((BUF) + (KK)*KHS + aoff + ((MB) + m_) * 1024); }
#define LDB4(BUF, KK)                                                         \
  { _Pragma("unroll") for (int n_ = 0; n_ < 4; ++n_)                          \
      bf[n_] = *(const short8v*)((BUF) + (KK)*KHS + boff + n_ * 1024); }
#define MMH(MH)                                                               \
  { _Pragma("unroll") for (int m_ = 0; m_ < FH; ++m_)                         \
      _Pragma("unroll") for (int n_ = 0; n_ < 4; ++n_)                        \
        acc[(MH)*FH + m_][n_] = MFMA16(af[m_], bf[n_], acc[(MH)*FH + m_][n_]); }
#define BAR __builtin_amdgcn_s_barrier()
#define WLGKM0 asm volatile("s_waitcnt lgkmcnt(0)" ::: "memory")

  const int NT = K >> 6;
  stA(smem, 0, 0); stB(smem, 0, 0); stA(smem, 0, 1); stB(smem, 0, 1);
  wvm<L>();
  BAR;
  for (int t = 0; t < NT; ++t) {
    char* cur = smem + (t & 1) * SBUF;
    char* nxt = smem + ((t + 1) & 1) * SBUF;
    const bool pf = (t + 1 < NT);
    LDAH(cur, 0, 0);
    LDB4(cur, 0);
    if (pf) { stA(nxt, t + 1, 0); stB(nxt, t + 1, 0); }
    BAR; WLGKM0;
    __builtin_amdgcn_s_setprio(1);
    MMH(0);
    __builtin_amdgcn_s_setprio(0);
    BAR;
    LDAH(cur, 0, FH);
    if (pf) { stA(nxt, t + 1, 1); stB(nxt, t + 1, 1); }
    BAR; WLGKM0;
    __builtin_amdgcn_s_setprio(1);
    MMH(1);
    __builtin_amdgcn_s_setprio(0);
    if (pf) wvm<2 * L>(); else wvm<0>();
    BAR;
    LDAH(cur, 1, 0);
    LDB4(cur, 1);
    BAR; WLGKM0;
    __builtin_amdgcn_s_setprio(1);
    MMH(0);
    __builtin_amdgcn_s_setprio(0);
    BAR;
    LDAH(cur, 1, FH);
    BAR; WLGKM0;
    __builtin_amdgcn_s_setprio(1);
    MMH(1);
    __builtin_amdgcn_s_setprio(0);
    if (pf) wvm<L>();
    BAR;
  }

  const int gr0 = blkrow + (wid >> 2) * (BM / 2) + kblk * 4;
  const int gc0 = blkcol + (wid & 3) * 64 + l15;
  if (EPI == 0) {
    float* C = (float*)C0 + (long long)ez * bsC;
#pragma unroll
    for (int mi = 0; mi < MF; ++mi)
#pragma unroll
      for (int n = 0; n < 4; ++n) {
        const int gc = gc0 + n * 16;
        const float badd = bias0 ? bias0[gc] : 0.f;
#pragma unroll
        for (int j = 0; j < 4; ++j)
          C[(size_t)(gr0 + mi * 16 + j) * ldc + gc] = acc[mi][n][j] * scale + badd;
      }
  } else {
    unsigned short* C = (unsigned short*)C0 + (long long)ez * bsC;
#pragma unroll
    for (int mi = 0; mi < MF; ++mi)
#pragma unroll
      for (int n = 0; n < 4; ++n) {
        const int gc = gc0 + n * 16;
        const float badd = bias0 ? bias0[gc] : 0.f;
#pragma unroll
        for (int j = 0; j < 4; ++j)
          C[(size_t)(gr0 + mi * 16 + j) * ldc + gc] = f2b(acc[mi][n][j] * scale + badd);
      }
  }
#undef LDAH
#undef LDB4
#undef MMH
#undef BAR
#undef WLGKM0
}

// ---------------------------------------------------------------------------
// fallback m97-style 128x128 GEMM (small-ws plan only)
template <int OMODE, bool BIAS, bool SCALE>
__global__ __launch_bounds__(256, 2) void gemm_bt(
    const unsigned short* __restrict__ A, int lda,
    const unsigned short* __restrict__ B, int ldb,
    void* __restrict__ Cp, int ldc,
    const float* __restrict__ bias, float scale, int K,
    long long bsA, long long bsB, long long bsC) {
  __shared__ unsigned short As[128 * 32];
  __shared__ unsigned short Bs[128 * 32];
  const int tid = threadIdx.x;
  A += (long long)blockIdx.z * bsA;
  B += (long long)blockIdx.z * bsB;
  const int brow = blockIdx.y * 128, bcol = blockIdx.x * 128;
  const int wid = tid >> 6, lane = tid & 63;
  const int wr = (wid >> 1) * 64, wc = (wid & 1) * 64;
  const int lrow = lane & 15, kblk = lane >> 4;
  f32x4 acc[4][4] = {};
  for (int kk = 0; kk < K; kk += 32) {
#pragma unroll
    for (int r = 0; r < 2; ++r) {
      int idx = r * 256 + tid;
      int row = idx >> 2, seg = (idx & 3) * 8;
      gload_lds16(A + (size_t)(brow + row) * lda + kk + seg, (char*)As + idx * 16);
      gload_lds16(B + (size_t)(bcol + row) * ldb + kk + seg, (char*)Bs + idx * 16);
    }
    __syncthreads();
    short8v af[4], bv[4];
#pragma unroll
    for (int m = 0; m < 4; ++m)
      af[m] = *(const short8v*)(As + (wr + m * 16 + lrow) * 32 + kblk * 8);
#pragma unroll
    for (int n = 0; n < 4; ++n)
      bv[n] = *(const short8v*)(Bs + (wc + n * 16 + lrow) * 32 + kblk * 8);
#pragma unroll
    for (int m = 0; m < 4; ++m)
#pragma unroll
      for (int n = 0; n < 4; ++n)
        acc[m][n] = MFMA16(af[m], bv[n], acc[m][n]);
    __syncthreads();
  }
  const int r0 = brow + wr + kblk * 4;
  const int c0 = bcol + wc + lrow;
  if (OMODE == 0) {
    float* C = (float*)Cp + (long long)blockIdx.z * bsC;
#pragma unroll
    for (int m = 0; m < 4; ++m)
#pragma unroll
      for (int n = 0; n < 4; ++n) {
        const int cc = c0 + n * 16;
        const float badd = BIAS ? bias[cc] : 0.f;
#pragma unroll
        for (int j = 0; j < 4; ++j) {
          float v = acc[m][n][j];
          if (SCALE) v *= scale;
          C[(size_t)(r0 + m * 16 + j) * ldc + cc] = v + badd;
        }
      }
  } else if (OMODE == 1) {
    unsigned short* C = (unsigned short*)Cp + (long long)blockIdx.z * bsC;
#pragma unroll
    for (int m = 0; m < 4; ++m)
#pragma unroll
      for (int n = 0; n < 4; ++n) {
        const int cc = c0 + n * 16;
        const float badd = BIAS ? bias[cc] : 0.f;
#pragma unroll
        for (int j = 0; j < 4; ++j) {
          float v = acc[m][n][j];
          if (SCALE) v *= scale;
          C[(size_t)(r0 + m * 16 + j) * ldc + cc] = f2b(v + badd);
        }
      }
  } else {
    unsigned short* C = (unsigned short*)Cp + (long long)blockIdx.z * bsC;
#pragma unroll
    for (int m = 0; m < 4; ++m)
#pragma unroll
      for (int n = 0; n < 4; ++n) {
        const int cc = c0 + n * 16;
        const float badd = BIAS ? bias[cc] : 0.f;
        ushort4v pk;
#pragma unroll
        for (int j = 0; j < 4; ++j) {
          float v = acc[m][n][j];
          if (SCALE) v *= scale;
          pk[j] = f2b(v + badd);
        }
        *(ushort4v*)(C + (size_t)cc * ldc + (r0 + m * 16)) = pk;
      }
  }
}

__global__ __launch_bounds__(256) void cvt_batch(const float* __restrict__ in,
                                                 unsigned short* __restrict__ out,
                                                 int n8) {
  for (int i = blockIdx.x * 256 + threadIdx.x; i < n8; i += gridDim.x * 256) {
    f32x4 a = *((const f32x4*)in + (size_t)i * 2);
    f32x4 b = *((const f32x4*)in + (size_t)i * 2 + 1);
    ushort8v o;
    o[0] = f2b(a[0]); o[1] = f2b(a[1]); o[2] = f2b(a[2]); o[3] = f2b(a[3]);
    o[4] = f2b(b[0]); o[5] = f2b(b[1]); o[6] = f2b(b[2]); o[7] = f2b(b[3]);
    *((ushort8v*)out + i) = o;
  }
}

extern "C" void kernel_launch(void* const* d_in, const int* in_sizes, int n_in,
                              void* d_out, int out_size, void* d_ws, size_t ws_size,
                              hipStream_t stream) {
  const float* x  = (const float*)d_in[0];
  const float* wq = (const float*)d_in[1];
  const float* bq = (const float*)d_in[2];
  const float* wk = (const float*)d_in[3];
  const float* bk = (const float*)d_in[4];
  const float* wv = (const float*)d_in[5];
  const float* bv = (const float*)d_in[6];
  const float* wo = (const float*)d_in[7];
  const float* bo = (const float*)d_in[8];
  float* out = (float*)d_out;
  char* ws = (char*)d_ws;

  const long long WELEM = 1024LL * 1024;
  const long long BATCH = 2048LL * 1024;
  const long long FULL  = 4 * BATCH;
  const long long SELEM = 2048LL * 2048;   // per-batch scores (elems)

  const size_t need_A = 8388608ull + 5ull * 16777216 + 4ull * 16777216;
  const size_t need_C = 8388608ull + 4ull * 4194304 + 16777216ull;

  if (ws_size >= need_A) {
    unsigned short* wqT = (unsigned short*)ws;
    unsigned short* wkT = wqT + WELEM;
    unsigned short* wvT = wkT + WELEM;   // wqT..wvT contiguous => [3072][1024]
    unsigned short* woT = wvT + WELEM;
    unsigned short* xb  = woT + WELEM;
    unsigned short* qb  = xb + FULL;
    unsigned short* kb  = qb + FULL;
    unsigned short* vt  = kb + FULL;     // Vt[1024][8192]
    unsigned short* ao  = vt + FULL;
    unsigned short* S   = ao + FULL;     // bf16 scores [4][2048][2048]

    hipFuncSetAttribute(reinterpret_cast<const void*>(&gemm256<1, 128>),
                        hipFuncAttributeMaxDynamicSharedMemorySize, 98304);
    hipFuncSetAttribute(reinterpret_cast<const void*>(&gemm256<0, 128>),
                        hipFuncAttributeMaxDynamicSharedMemorySize, 98304);

    // prep: weight transposes (z=0..3) + x->bf16 (z=4) in ONE launch
    prep<<<dim3(16, 16, 5), 256, 0, stream>>>(x, wq, wk, wv, wo, xb,
                                              wqT, wkT, wvT, woT);

    // fused QKV (natural mapping): grid (24,64)
    gemm_qkv128<<<dim3(24, 64), 256, 0, stream>>>(
        xb, wqT, qb, kb, vt, bq, bk, bv);
    // QK^T (batched) on high-occupancy 128^2: grid (16,16,4) = 1024 blocks
    gemm128<1><<<dim3(16, 16, 4), 256, 0, stream>>>(
        qb, 1024, kb, 1024, S, 2048, nullptr, 0.03125f, 1024,
        BATCH, BATCH, SELEM);
    softmax_bf16<<<dim3(2048, 4), 256, 0, stream>>>(S, SELEM);
    // PV (batched): grid (4,16,4)
    gemm256<1, 128><<<dim3(4, 16, 4), 512, 98304, stream>>>(
        S, 2048, vt, 8192, ao, 1024, nullptr, 1.f, 2048,
        SELEM, 2048, BATCH);
    // out-proj: grid (4,64)
    gemm256<0, 128><<<dim3(4, 64, 1), 512, 98304, stream>>>(
        ao, 1024, woT, 1024, out, 1024, bo, 1.f, 1024, 0, 0, 0);
  } else if (ws_size >= need_C) {
    unsigned short* wqT = (unsigned short*)ws;
    unsigned short* wkT = wqT + WELEM;
    unsigned short* wvT = wkT + WELEM;
    unsigned short* woT = wvT + WELEM;
    unsigned short* xb  = woT + WELEM;
    unsigned short* qb  = xb + BATCH;
    unsigned short* kb  = qb + BATCH;
    unsigned short* vtb = kb + BATCH;
    float* S = (float*)(vtb + BATCH);

    prep<<<dim3(16, 16, 4), 256, 0, stream>>>(x, wq, wk, wv, wo, xb,
                                              wqT, wkT, wvT, woT);

    for (int b = 0; b < 4; ++b) {
      cvt_batch<<<1024, 256, 0, stream>>>(x + b * BATCH, xb, (int)(BATCH / 8));
      dim3 gqkv(8, 16);
      gemm_bt<1, true, false><<<gqkv, 256, 0, stream>>>(xb, 1024, wqT, 1024, qb, 1024, bq, 1.f, 1024, 0, 0, 0);
      gemm_bt<1, true, false><<<gqkv, 256, 0, stream>>>(xb, 1024, wkT, 1024, kb, 1024, bk, 1.f, 1024, 0, 0, 0);
      gemm_bt<2, true, false><<<gqkv, 256, 0, stream>>>(xb, 1024, wvT, 1024, vtb, 2048, bv, 1.f, 1024, 0, 0, 0);
      gemm_bt<0, false, true><<<dim3(16, 16), 256, 0, stream>>>(
          qb, 1024, kb, 1024, S, 2048, nullptr, 0.03125f, 1024, 0, 0, 0);
      softmax_rows<<<dim3(2048, 1), 256, 0, stream>>>(S, 0);
      gemm_bt<1, false, false><<<dim3(8, 16), 256, 0, stream>>>(
          (const unsigned short*)S, 4096, vtb, 2048, xb, 1024, nullptr, 1.f, 2048, 0, 0, 0);
      gemm_bt<0, true, false><<<dim3(8, 16), 256, 0, stream>>>(
          xb, 1024, woT, 1024, out + b * BATCH, 1024, bo, 1.f, 1024, 0, 0, 0);
    }
  }
}